// Round 1
// baseline (210.239 us; speedup 1.0000x reference)
//
#include <hip/hip_runtime.h>

#define LOG2E 1.44269504088896340736f

// One wave (64 threads) per block; 16 batch rows per wave; 4 lanes per row,
// lane q in {0,1,2,3} owns gate type {i,f,g,o} (3 columns each of the 12).
__global__ __launch_bounds__(64, 1)
void lstm_fused_kernel(const float* __restrict__ X,    // [B,T,F] = [8192,512,16]
                       const float* __restrict__ Wg,   // [16,12]
                       const float* __restrict__ Ug,   // [3,12]
                       const float* __restrict__ bg,   // [12]
                       const float* __restrict__ Wd,   // [3]
                       const float* __restrict__ bd,   // [1]
                       float* __restrict__ out)        // [8192]
{
    constexpr int T = 512;
    const int lane = threadIdx.x;      // 0..63
    const int g    = lane >> 2;        // row group within wave, 0..15
    const int q    = lane & 3;         // gate type
    const int b    = blockIdx.x * 16 + g;

    // Per-lane weight slices (held in VGPRs; tiny, loaded once)
    float w[16][3];
#pragma unroll
    for (int f = 0; f < 16; ++f)
#pragma unroll
        for (int k = 0; k < 3; ++k)
            w[f][k] = Wg[f * 12 + q * 3 + k];

    float u[3][3];
#pragma unroll
    for (int j = 0; j < 3; ++j)
#pragma unroll
        for (int k = 0; k < 3; ++k)
            u[j][k] = Ug[j * 12 + q * 3 + k];

    float bias0 = bg[q * 3 + 0], bias1 = bg[q * 3 + 1], bias2 = bg[q * 3 + 2];
    const float wd0 = Wd[0], wd1 = Wd[1], wd2 = Wd[2], bdv = bd[0];

    // Branchless activation: sigmoid for q in {0,1,3}, tanh for q==2.
    // act(z) = pa * rcp(1 + exp2(z*pre)) + pb
    const bool is_g = (q == 2);
    const float pre = is_g ? (-2.0f * LOG2E) : (-LOG2E);
    const float pa  = is_g ? 2.0f : 1.0f;
    const float pb  = is_g ? -1.0f : 0.0f;

    float h0 = 0.f, h1 = 0.f, h2 = 0.f;
    float c0 = 0.f, c1 = 0.f, c2 = 0.f;

    const float4* X4 = reinterpret_cast<const float4*>(X) + (size_t)b * (T * 4);

    // Software pipeline: 4 timesteps in flight (statically indexed after unroll)
    float4 xb[4][4];
#pragma unroll
    for (int s = 0; s < 4; ++s)
#pragma unroll
        for (int p = 0; p < 4; ++p)
            xb[s][p] = X4[s * 4 + p];

    const int lb = lane & ~3;   // group base lane

    for (int t0 = 0; t0 < T; t0 += 4) {
#pragma unroll
        for (int s = 0; s < 4; ++s) {
            const float4 v0 = xb[s][0];
            const float4 v1 = xb[s][1];
            const float4 v2 = xb[s][2];
            const float4 v3 = xb[s][3];
            // prefetch t0+4+s (clamped; tail redundantly reloads last step)
            {
                int tn = t0 + 4 + s;
                tn = (tn < T) ? tn : (T - 1);
                const size_t o = (size_t)tn * 4;
                xb[s][0] = X4[o + 0];
                xb[s][1] = X4[o + 1];
                xb[s][2] = X4[o + 2];
                xb[s][3] = X4[o + 3];
            }

            const float xv[16] = {v0.x, v0.y, v0.z, v0.w,
                                  v1.x, v1.y, v1.z, v1.w,
                                  v2.x, v2.y, v2.z, v2.w,
                                  v3.x, v3.y, v3.z, v3.w};
            float z0 = bias0, z1 = bias1, z2 = bias2;
#pragma unroll
            for (int f = 0; f < 16; ++f) {
                z0 = fmaf(xv[f], w[f][0], z0);
                z1 = fmaf(xv[f], w[f][1], z1);
                z2 = fmaf(xv[f], w[f][2], z2);
            }
            z0 = fmaf(h0, u[0][0], z0); z0 = fmaf(h1, u[1][0], z0); z0 = fmaf(h2, u[2][0], z0);
            z1 = fmaf(h0, u[0][1], z1); z1 = fmaf(h1, u[1][1], z1); z1 = fmaf(h2, u[2][1], z1);
            z2 = fmaf(h0, u[0][2], z2); z2 = fmaf(h1, u[1][2], z2); z2 = fmaf(h2, u[2][2], z2);

            float e0 = __builtin_amdgcn_exp2f(z0 * pre);
            float e1 = __builtin_amdgcn_exp2f(z1 * pre);
            float e2 = __builtin_amdgcn_exp2f(z2 * pre);
            const float val0 = fmaf(pa, __builtin_amdgcn_rcpf(1.0f + e0), pb);
            const float val1 = fmaf(pa, __builtin_amdgcn_rcpf(1.0f + e1), pb);
            const float val2 = fmaf(pa, __builtin_amdgcn_rcpf(1.0f + e2), pb);

            // gather i,f,g,o (per hidden unit k) from the 4 lanes of this row
            const float i0 = __shfl(val0, lb + 0, 64);
            const float i1 = __shfl(val1, lb + 0, 64);
            const float i2 = __shfl(val2, lb + 0, 64);
            const float f0 = __shfl(val0, lb + 1, 64);
            const float f1 = __shfl(val1, lb + 1, 64);
            const float f2 = __shfl(val2, lb + 1, 64);
            const float g0 = __shfl(val0, lb + 2, 64);
            const float g1 = __shfl(val1, lb + 2, 64);
            const float g2 = __shfl(val2, lb + 2, 64);
            const float o0 = __shfl(val0, lb + 3, 64);
            const float o1 = __shfl(val1, lb + 3, 64);
            const float o2 = __shfl(val2, lb + 3, 64);

            c0 = fmaf(f0, c0, i0 * g0);
            c1 = fmaf(f1, c1, i1 * g1);
            c2 = fmaf(f2, c2, i2 * g2);

            // h = o * tanh(c)   (redundant across the 4 lanes; keeps h local)
            float ec0 = __builtin_amdgcn_exp2f(c0 * (-2.0f * LOG2E));
            float ec1 = __builtin_amdgcn_exp2f(c1 * (-2.0f * LOG2E));
            float ec2 = __builtin_amdgcn_exp2f(c2 * (-2.0f * LOG2E));
            h0 = o0 * fmaf(2.0f, __builtin_amdgcn_rcpf(1.0f + ec0), -1.0f);
            h1 = o1 * fmaf(2.0f, __builtin_amdgcn_rcpf(1.0f + ec1), -1.0f);
            h2 = o2 * fmaf(2.0f, __builtin_amdgcn_rcpf(1.0f + ec2), -1.0f);
        }
    }

    if (q == 0) {
        float acc = bdv;
        acc = fmaf(h0, wd0, acc);
        acc = fmaf(h1, wd1, acc);
        acc = fmaf(h2, wd2, acc);
        float e = __builtin_amdgcn_exp2f(-LOG2E * acc);
        out[b] = __builtin_amdgcn_rcpf(1.0f + e);
    }
}

extern "C" void kernel_launch(void* const* d_in, const int* in_sizes, int n_in,
                              void* d_out, int out_size, void* d_ws, size_t ws_size,
                              hipStream_t stream) {
    const float* X  = (const float*)d_in[0];
    const float* W  = (const float*)d_in[1];
    const float* U  = (const float*)d_in[2];
    const float* bg = (const float*)d_in[3];
    const float* Wd = (const float*)d_in[4];
    const float* bd = (const float*)d_in[5];
    float* out = (float*)d_out;

    dim3 grid(8192 / 16);   // 512 blocks, one wave each
    dim3 block(64);
    hipLaunchKernelGGL(lstm_fused_kernel, grid, block, 0, stream,
                       X, W, U, bg, Wd, bd, out);
}

// Round 2
// 158.035 us; speedup vs baseline: 1.3303x; 1.3303x over previous
//
#include <hip/hip_runtime.h>

#define LOG2E 1.44269504088896340736f

// Bit-exact lane swizzle (BitMode): src_lane = ((lane & and) | or) ^ xor, per 32-lane half.
// offset imm = (xor<<10) | (or<<5) | and
#define SWZ(v, imm) __int_as_float(__builtin_amdgcn_ds_swizzle(__float_as_int(v), (imm)))

// 16 lanes per batch row. Lane layout within wave: bits[1:0]=k (hidden unit,
// k==3 duplicates k==2), bits[3:2]=q (gate i/f/g/o), bits[5:4]=row-in-wave.
// 4 rows/wave, 16 rows/block(256 thr), 512 blocks -> 2048 waves (8/CU).
__global__ __launch_bounds__(256, 1)
void lstm_fused16_kernel(const float* __restrict__ X,    // [8192,512,16]
                         const float* __restrict__ Wg,   // [16,12]
                         const float* __restrict__ Ug,   // [3,12]
                         const float* __restrict__ bg,   // [12]
                         const float* __restrict__ Wd,   // [3]
                         const float* __restrict__ bd,   // [1]
                         float* __restrict__ out)        // [8192]
{
    constexpr int T = 512;
    const int tid = threadIdx.x;
    const int lr  = tid & 15;         // lane within row group
    const int q   = (lr >> 2) & 3;    // gate type: 0=i,1=f,2=g,3=o
    const int k   = lr & 3;           // hidden unit (3 == duplicate of 2)
    const int kk  = (k == 3) ? 2 : k;
    const int col = q * 3 + kk;       // column in the [.,12] gate matrices
    const int b   = blockIdx.x * 16 + (tid >> 4);

    // Per-lane weight column (16 + 3 + 1 regs)
    float w[16];
#pragma unroll
    for (int f = 0; f < 16; ++f) w[f] = Wg[f * 12 + col];
    const float u0 = Ug[0 * 12 + col];
    const float u1 = Ug[1 * 12 + col];
    const float u2 = Ug[2 * 12 + col];
    const float bias = bg[col];
    const float wd0 = Wd[0], wd1 = Wd[1], wd2 = Wd[2], bdv = bd[0];

    // Branchless activation: sigmoid for q in {0,1,3}, tanh for q==2.
    // act(z) = pa * rcp(1 + exp2(z*pre)) + pb
    const bool is_g = (q == 2);
    const float pre = is_g ? (-2.0f * LOG2E) : (-LOG2E);
    const float pa  = is_g ? 2.0f : 1.0f;
    const float pb  = is_g ? -1.0f : 0.0f;

    float h0 = 0.f, h1 = 0.f, h2 = 0.f;
    float c  = 0.f;                   // this lane's own c_k

    const float4* X4 = reinterpret_cast<const float4*>(X) + (size_t)b * (T * 4);

    // 4-step software pipeline (statically indexed after unroll)
    float4 xb[4][4];
#pragma unroll
    for (int s = 0; s < 4; ++s)
#pragma unroll
        for (int p = 0; p < 4; ++p)
            xb[s][p] = X4[s * 4 + p];

    for (int t0 = 0; t0 < T; t0 += 4) {
#pragma unroll
        for (int s = 0; s < 4; ++s) {
            const float4 v0 = xb[s][0];
            const float4 v1 = xb[s][1];
            const float4 v2 = xb[s][2];
            const float4 v3 = xb[s][3];
            // prefetch t0+4+s (clamped; tail redundantly reloads last step)
            {
                int tn = t0 + 4 + s;
                tn = (tn < T) ? tn : (T - 1);
                const size_t o = (size_t)tn * 4;
                xb[s][0] = X4[o + 0];
                xb[s][1] = X4[o + 1];
                xb[s][2] = X4[o + 2];
                xb[s][3] = X4[o + 3];
            }

            const float xv[16] = {v0.x, v0.y, v0.z, v0.w,
                                  v1.x, v1.y, v1.z, v1.w,
                                  v2.x, v2.y, v2.z, v2.w,
                                  v3.x, v3.y, v3.z, v3.w};
            // x·W part (off the recurrent critical path)
            float zx = bias;
#pragma unroll
            for (int f = 0; f < 16; ++f) zx = fmaf(xv[f], w[f], zx);

            // recurrent part
            float z = fmaf(h0, u0, zx);
            z = fmaf(h1, u1, z);
            z = fmaf(h2, u2, z);

            const float e   = __builtin_amdgcn_exp2f(z * pre);
            const float val = fmaf(pa, __builtin_amdgcn_rcpf(1.0f + e), pb);

            // gather i,f,g,o for this lane's unit k: broadcast from lane (q',k)
            // src = (lane & 0b10011) | (q'<<2)   -> and=0x13, or=q'<<2
            const float iv = SWZ(val, 0x013);   // q'=0
            const float fv = SWZ(val, 0x093);   // q'=1
            const float gv = SWZ(val, 0x113);   // q'=2
            const float ov = SWZ(val, 0x193);   // q'=3

            c = fmaf(fv, c, iv * gv);

            const float ec = __builtin_amdgcn_exp2f(c * (-2.0f * LOG2E));
            const float th = fmaf(2.0f, __builtin_amdgcn_rcpf(1.0f + ec), -1.0f);
            const float hk = ov * th;

            // broadcast h_k' to everyone: src = (lane & 0b11100) | k'
            h0 = SWZ(hk, 0x01C);
            h1 = SWZ(hk, 0x03C);
            h2 = SWZ(hk, 0x05C);
        }
    }

    if (lr == 0) {
        float acc = bdv;
        acc = fmaf(h0, wd0, acc);
        acc = fmaf(h1, wd1, acc);
        acc = fmaf(h2, wd2, acc);
        const float e = __builtin_amdgcn_exp2f(-LOG2E * acc);
        out[b] = __builtin_amdgcn_rcpf(1.0f + e);
    }
}

extern "C" void kernel_launch(void* const* d_in, const int* in_sizes, int n_in,
                              void* d_out, int out_size, void* d_ws, size_t ws_size,
                              hipStream_t stream) {
    const float* X  = (const float*)d_in[0];
    const float* W  = (const float*)d_in[1];
    const float* U  = (const float*)d_in[2];
    const float* bg = (const float*)d_in[3];
    const float* Wd = (const float*)d_in[4];
    const float* bd = (const float*)d_in[5];
    float* out = (float*)d_out;

    dim3 grid(8192 / 16);   // 512 blocks x 256 threads = 2048 waves
    dim3 block(256);
    hipLaunchKernelGGL(lstm_fused16_kernel, grid, block, 0, stream,
                       X, W, U, bg, Wd, bd, out);
}